// Round 9
// baseline (112.078 us; speedup 1.0000x reference)
//
#include <hip/hip_runtime.h>

// Fused LSTM B=16384, T=60, IN=1, H=50, OUT=1 — fully-in-register recurrence.
// 1024 blocks x 64 thr (1 wave = 16 batches). ZERO LDS / barriers / shuffles
// in the recurrence: A-rows permuted so tile T maps unit u = 8g+(T&7)+32(T>>3)
// to lane group g (gate = acc reg r, since D row = 4g+r). Then lane (g,cl)'s
// 16 produced h values (tiles 0..15, batch cl) are EXACTLY the k-slots
// 8g..8g+7 / 32+8g..+7 of its own next-step B-fragments (B: k = 8*(l>>4)+e,
// col = l&15). h -> fp16 -> rebuild B0/B1 in registers. Bias rides k=62,
// x_t rides k=63 (g==3 lanes overwrite those 2 slots). Pad units (>=50)
// have zero A-rows -> produce h=0 -> feed zero A-columns: self-consistent.
// LDS only: w_lin broadcast (4 b128/step) + x (1 b32/step).
// R8 post-mortem: cross-wave M-split duplicates H reads (64KB/step/CU LDS
// return for 4KB unique, 8-way aliased) — this removes the exchange itself.

namespace {
constexpr int TS = 60;

typedef _Float16 half8 __attribute__((ext_vector_type(8)));
typedef float f32x4 __attribute__((ext_vector_type(4)));

__device__ __forceinline__ float fexp2(float x) { return __builtin_amdgcn_exp2f(x); }
__device__ __forceinline__ float frcp(float x) { return __builtin_amdgcn_rcpf(x); }
__device__ __forceinline__ f32x4 mfma16(half8 a, half8 b, f32x4 c) {
  return __builtin_amdgcn_mfma_f32_16x16x32_f16(a, b, c, 0, 0, 0);
}
}  // namespace

__global__ __launch_bounds__(64, 1) void lstm_reg(
    const float* __restrict__ x,      // [B][60]
    const float* __restrict__ w_ih,   // [200]
    const float* __restrict__ w_hh,   // [200][50]
    const float* __restrict__ b_ih,   // [200]
    const float* __restrict__ b_hh,   // [200]
    const float* __restrict__ w_lin,  // [3000]
    const float* __restrict__ b_lin,  // [1]
    float* __restrict__ out)          // [B]
{
  __shared__ float WL[TS * 64];  // 15.36 KB, [t][u] 0-padded (identity u)
  __shared__ float XL[TS * 16];  // 3.75 KB, [t][cl]

  const int lane = threadIdx.x;
  const int g = lane >> 4;   // k-group / unit-block owner
  const int cl = lane & 15;  // batch-in-wave; A/B/D column
  const long bbase = (long)blockIdx.x * 16;

  // ---- stage XL[t][b] ----
  for (int i = lane; i < TS * 16; i += 64) {
    const int b = i / TS, t = i - b * TS;
    XL[t * 16 + b] = x[bbase * TS + i];
  }
  // ---- stage WL[t][u] ----
  for (int i = lane; i < TS * 64; i += 64) {
    const int t = i >> 6, u = i & 63;
    WL[i] = (u < 50) ? w_lin[t * 50 + u] : 0.0f;
  }

  // ---- gather A-fragments (fp32 -> fp16), once, direct from global ----
  // A-row m = cl of tile T: gate = cl&3, unit = 8*(cl>>2) + (T&7) + 32*(T>>3)
  // element e of chunk kc: k = 32kc + 8g + e. k<50: w_hh col; 62: bias; 63: w_ih.
  half8 A[16][2];
  {
    const int gateA = cl & 3, urA = cl >> 2;
#pragma unroll
    for (int T = 0; T < 16; ++T) {
      const int uA = 8 * urA + (T & 7) + 32 * (T >> 3);
      const int orig = gateA * 50 + uA;
      const bool valid = (uA < 50);
#pragma unroll
      for (int kc = 0; kc < 2; ++kc) {
        half8 fr;
#pragma unroll
        for (int e = 0; e < 8; ++e) {
          const int k = kc * 32 + 8 * g + e;
          float v = 0.0f;
          if (valid) {
            if (k < 50) v = w_hh[orig * 50 + k];
            else if (k == 62) v = b_ih[orig] + b_hh[orig];
            else if (k == 63) v = w_ih[orig];
          }
          fr[e] = (_Float16)v;
        }
        A[T][kc] = fr;
      }
    }
  }
  __syncthreads();  // 1-wave barrier (XL/WL visibility)

  // ---- initial B-fragments: h=0; g==3 carries (bias=1, x_0) at k=62,63 ----
  half8 B0 = {};
  half8 B1 = {};
  if (g == 3) {
    B1[6] = (_Float16)1.0f;
    B1[7] = (_Float16)XL[cl];
  }

  float c[16];
#pragma unroll
  for (int T = 0; T < 16; ++T) c[T] = 0.0f;
  float oacc = 0.0f;

  constexpr float L1 = 1.4426950408889634f;  // log2(e)
  constexpr float L2 = 2.8853900817779268f;  // 2*log2(e)

#pragma unroll 1
  for (int t = 0; t < TS; ++t) {
    f32x4 acc[16];
#pragma unroll
    for (int T = 0; T < 16; ++T) {
      f32x4 a = {0.f, 0.f, 0.f, 0.f};
      a = mfma16(A[T][0], B0, a);
      a = mfma16(A[T][1], B1, a);
      acc[T] = a;
    }
    // w_lin for this lane's 16 units (broadcast reads, conflict-free)
    const f32x4 wla = *(const f32x4*)&WL[t * 64 + 8 * g];
    const f32x4 wlb = *(const f32x4*)&WL[t * 64 + 8 * g + 4];
    const f32x4 wlc = *(const f32x4*)&WL[t * 64 + 32 + 8 * g];
    const f32x4 wld = *(const f32x4*)&WL[t * 64 + 32 + 8 * g + 4];
    const int tn = (t + 1 < TS) ? (t + 1) : (TS - 1);
    const float xnext = XL[tn * 16 + cl];

    _Float16 hh[16];
#pragma unroll
    for (int T = 0; T < 16; ++T) {
      // batched reciprocal: 1 rcp serves sigm(i),sigm(f),sigm(o),tanh(g)
      const float E1 = fexp2(-L1 * acc[T][0]);
      const float E2 = fexp2(-L1 * acc[T][1]);
      const float E3 = fexp2(-L1 * acc[T][3]);
      const float E4 = fexp2(L2 * acc[T][2]);
      const float P1 = 1.0f + E1, P2 = 1.0f + E2;
      const float P3 = 1.0f + E3, P4 = 1.0f + E4;
      const float p12 = P1 * P2, p34 = P3 * P4;
      const float r = frcp(p12 * p34);
      const float r12 = r * p34, r34 = r * p12;
      const float si = r12 * P2, sf = r12 * P1, so = r34 * P4;
      const float tg = fmaf(-2.0f, r34 * P3, 1.0f);
      const float cn = fmaf(sf, c[T], si * tg);
      c[T] = cn;
      const float Ec = fexp2(L2 * cn);
      const float tc = fmaf(-2.0f, frcp(1.0f + Ec), 1.0f);
      const float hn = so * tc;
      const float wv = (T < 4) ? wla[T]
                     : (T < 8) ? wlb[T - 4]
                     : (T < 12) ? wlc[T - 8] : wld[T - 12];
      oacc = fmaf(hn, wv, oacc);
      hh[T] = (_Float16)hn;
    }

    // ---- rebuild next-step B-fragments entirely in registers ----
    half8 nB0, nB1;
#pragma unroll
    for (int e = 0; e < 8; ++e) {
      nB0[e] = hh[e];       // k = 8g+e   <- tile e
      nB1[e] = hh[8 + e];   // k = 32+8g+e <- tile 8+e
    }
    if (g == 3) {  // k=62 -> 1.0 (bias col), k=63 -> x_{t+1}
      nB1[6] = (_Float16)1.0f;
      nB1[7] = (_Float16)xnext;
    }
    B0 = nB0;
    B1 = nB1;
  }

  // ---- reduce oacc over the 4 g-groups (lanes cl, cl+16, cl+32, cl+48) ----
  oacc += __shfl_xor(oacc, 32);
  oacc += __shfl_xor(oacc, 16);
  if (lane < 16) out[bbase + lane] = oacc + b_lin[0];
}

extern "C" void kernel_launch(void* const* d_in, const int* in_sizes, int n_in,
                              void* d_out, int out_size, void* d_ws, size_t ws_size,
                              hipStream_t stream) {
  const float* x     = (const float*)d_in[0];
  const float* w_ih  = (const float*)d_in[1];
  const float* w_hh  = (const float*)d_in[2];
  const float* b_ih  = (const float*)d_in[3];
  const float* b_hh  = (const float*)d_in[4];
  const float* w_lin = (const float*)d_in[5];
  const float* b_lin = (const float*)d_in[6];
  float* out = (float*)d_out;

  dim3 grid(16384 / 16);  // 1024 single-wave blocks (1 wave/SIMD)
  dim3 block(64);
  lstm_reg<<<grid, block, 0, stream>>>(x, w_ih, w_hh, b_ih, b_hh, w_lin,
                                       b_lin, out);
}

// Round 10
// 91.352 us; speedup vs baseline: 1.2269x; 1.2269x over previous
//
#include <hip/hip_runtime.h>

// Fused LSTM B=16384, T=60, IN=1, H=50, OUT=1 — R6 structure, de-fatted.
// 512 blocks x 256 thr (4 waves). Block owns 32 batches = two independent
// 16-batch groups; ONE barrier/step. Changes vs R6 (93 us):
//  * 13 M-tiles (not 16): unit u = 4T+du, D-row = 4*du+gate -> tiles 13..15
//    are pure padding and are DROPPED. Waves own tiles {0-3,4-7,8-11,12}.
//    Per block-step: 52 MFMA (was 64), 26 nonlin slots (was 32).
//  * batched 4-term reciprocal (R8-verified): 7 trans/slot (was 10).
//  * identity k-map: k = unit; h(u) -> LDS slot u; bias k=62, x k=63.
// H fp16 [row=cl][64 k] chunk(16B)-XOR-swizzled, dbuf per group. Weights
// fp16(hi) A-frags in VGPRs. c fp32 in regs. w_lin/x staged in LDS.

namespace {
constexpr int TS = 60;

typedef _Float16 half8 __attribute__((ext_vector_type(8)));
typedef _Float16 half2v __attribute__((ext_vector_type(2)));
typedef float f32x4 __attribute__((ext_vector_type(4)));

__device__ __forceinline__ float fexp2(float x) { return __builtin_amdgcn_exp2f(x); }
__device__ __forceinline__ float frcp(float x) { return __builtin_amdgcn_rcpf(x); }
__device__ __forceinline__ f32x4 mfma16(half8 a, half8 b, f32x4 c) {
  return __builtin_amdgcn_mfma_f32_16x16x32_f16(a, b, c, 0, 0, 0);
}
}  // namespace

__global__ __launch_bounds__(256, 2) void lstm_t13(
    const float* __restrict__ x,      // [B][60]
    const float* __restrict__ w_ih,   // [200]
    const float* __restrict__ w_hh,   // [200][50]
    const float* __restrict__ b_ih,   // [200]
    const float* __restrict__ b_hh,   // [200]
    const float* __restrict__ w_lin,  // [3000]
    const float* __restrict__ b_lin,  // [1]
    float* __restrict__ out)          // [B]
{
  __shared__ __align__(16) _Float16 Hs[2][2][16 * 64];  // [grp][buf] 8 KB
  __shared__ float WL[TS * 64];   // 15.36 KB [t][u], 0-padded
  __shared__ float XL[TS * 32];   // 7.68 KB [t][b]
  __shared__ float OB[4][2][16];  // 512 B

  const int tid = threadIdx.x;
  const int lane = tid & 63;
  const int wv = tid >> 6;   // 0..3
  const int g = lane >> 4;   // lane quad-group: B k-owner, D row-block (du)
  const int cl = lane & 15;  // batch-in-group; A/B/D column
  const int s8 = cl & 7;
  const long bbase = (long)blockIdx.x * 32;

  // ---- stage XL[t][b] ----
  for (int i = tid; i < TS * 32; i += 256) {
    const int b = i / TS, t = i - b * TS;
    XL[t * 32 + b] = x[bbase * TS + i];
  }
  // ---- stage WL[t][u] ----
  for (int i = tid; i < TS * 64; i += 256) {
    const int t = i >> 6, u = i & 63;
    WL[i] = (u < 50) ? w_lin[t * 50 + u] : 0.0f;
  }
  // ---- zero all H buffers (h0 = 0; pad k-slots stay 0 forever) ----
  for (int i = tid; i < 2048; i += 256) ((unsigned*)Hs)[i] = 0u;

  // ---- gather this wave's A-fragments (fp32 -> fp16), once ----
  // tile T: A-row m=cl -> (du=cl>>2, gate=cl&3), unit uA = 4T+du,
  // orig gate-row = gate*50+uA. k-slot: 32kc+8g+e; k<50 -> w_hh col k
  // (identity: k = source unit), 62 -> bias, 63 -> w_ih.
  half8 A[4][2];
  {
    const int gate = cl & 3, du = cl >> 2;
    const int ntile = (wv < 3) ? 4 : 1;
#pragma unroll
    for (int tau = 0; tau < 4; ++tau) {
      const int T = (wv < 3) ? (4 * wv + tau) : 12;
      const int uA = 4 * T + du;
      const int orig = gate * 50 + uA;
      const bool valid = (tau < ntile) && (uA < 50);
#pragma unroll
      for (int kc = 0; kc < 2; ++kc) {
        half8 fr;
#pragma unroll
        for (int e = 0; e < 8; ++e) {
          const int k = kc * 32 + 8 * g + e;
          float v = 0.0f;
          if (valid) {
            if (k < 50) v = w_hh[orig * 50 + k];
            else if (k == 62) v = b_ih[orig] + b_hh[orig];
            else if (k == 63) v = w_ih[orig];
          }
          fr[e] = (_Float16)v;
        }
        A[tau][kc] = fr;
      }
    }
  }
  __syncthreads();

  // ---- specials in buf0 (both groups): k=62 -> 1.0, k=63 -> x_0 ----
  if (wv == 3 && g == 3) {
#pragma unroll
    for (int grp = 0; grp < 2; ++grp) {
      const half2v sp = {(_Float16)1.0f, (_Float16)XL[grp * 16 + cl]};
      *(half2v*)&Hs[grp][0][cl * 64 + ((7 ^ s8) << 3) + 6] = sp;
    }
  }
  __syncthreads();

  // B-frag read offsets (halves): kc0 -> chunk g, kc1 -> chunk 4+g
  const int rh0 = cl * 64 + ((g ^ s8) << 3);
  const int rh1 = cl * 64 + (((4 | g) ^ s8) << 3);

  float c[2][4] = {{0.f, 0.f, 0.f, 0.f}, {0.f, 0.f, 0.f, 0.f}};
  float oacc[2] = {0.f, 0.f};

  constexpr float L1 = 1.4426950408889634f;  // log2(e)
  constexpr float L2 = 2.8853900817779268f;  // 2*log2(e)

#define DO_TILES(NT, TBASE)                                                   \
  {                                                                           \
    f32x4 acc[2][NT];                                                         \
    _Pragma("unroll") for (int grp = 0; grp < 2; ++grp) {                     \
      _Pragma("unroll") for (int tau = 0; tau < NT; ++tau) {                  \
        f32x4 a = {0.f, 0.f, 0.f, 0.f};                                       \
        a = mfma16(A[tau][0], grp ? B0b : B0a, a);                            \
        a = mfma16(A[tau][1], grp ? B1b : B1a, a);                            \
        acc[grp][tau] = a;                                                    \
      }                                                                       \
    }                                                                         \
    _Pragma("unroll") for (int tau = 0; tau < NT; ++tau) {                    \
      const int u = 4 * (TBASE + tau) + g;                                    \
      const float wlv = WL[t * 64 + u];                                       \
      const int widx = cl * 64 + (((u >> 3) ^ s8) << 3) + (u & 7);            \
      _Pragma("unroll") for (int grp = 0; grp < 2; ++grp) {                   \
        const float E1 = fexp2(-L1 * acc[grp][tau][0]);                       \
        const float E2 = fexp2(-L1 * acc[grp][tau][1]);                       \
        const float E3 = fexp2(-L1 * acc[grp][tau][3]);                       \
        const float E4 = fexp2(L2 * acc[grp][tau][2]);                        \
        const float P1 = 1.0f + E1, P2 = 1.0f + E2;                           \
        const float P3 = 1.0f + E3, P4 = 1.0f + E4;                           \
        const float p12 = P1 * P2, p34 = P3 * P4;                             \
        const float r = frcp(p12 * p34);                                      \
        const float r12 = r * p34, r34 = r * p12;                             \
        const float si = r12 * P2, sf = r12 * P1, so = r34 * P4;              \
        const float tg = fmaf(-2.0f, r34 * P3, 1.0f);                         \
        const float cn = fmaf(sf, c[grp][tau], si * tg);                      \
        c[grp][tau] = cn;                                                     \
        const float Ec = fexp2(L2 * cn);                                      \
        const float tc = fmaf(-2.0f, frcp(1.0f + Ec), 1.0f);                  \
        const float hn = so * tc;                                             \
        oacc[grp] = fmaf(hn, wlv, oacc[grp]);                                 \
        (grp ? HN1 : HN0)[widx] = (_Float16)hn;                               \
      }                                                                       \
    }                                                                         \
  }

#pragma unroll 1
  for (int t = 0; t < TS; ++t) {
    const int p = t & 1;
    const _Float16* HR0 = &Hs[0][p][0];
    const _Float16* HR1 = &Hs[1][p][0];
    _Float16* HN0 = &Hs[0][p ^ 1][0];
    _Float16* HN1 = &Hs[1][p ^ 1][0];
    const half8 B0a = *(const half8*)&HR0[rh0];
    const half8 B1a = *(const half8*)&HR0[rh1];
    const half8 B0b = *(const half8*)&HR1[rh0];
    const half8 B1b = *(const half8*)&HR1[rh1];

    if (wv < 3) {
      const int tb = 4 * wv;
      DO_TILES(4, tb);
    } else {
      DO_TILES(1, 12);
      if (g == 3) {  // specials for next step: k=62 -> 1.0, k=63 -> x_{t+1}
        const int tn = (t + 1 < TS) ? (t + 1) : (TS - 1);
        const half2v spa = {(_Float16)1.0f, (_Float16)XL[tn * 32 + cl]};
        const half2v spb = {(_Float16)1.0f, (_Float16)XL[tn * 32 + 16 + cl]};
        *(half2v*)&HN0[cl * 64 + ((7 ^ s8) << 3) + 6] = spa;
        *(half2v*)&HN1[cl * 64 + ((7 ^ s8) << 3) + 6] = spb;
      }
    }
    __syncthreads();
  }
#undef DO_TILES

  // ---- reduce over g (shfl), then over waves (LDS) ----
  oacc[0] += __shfl_xor(oacc[0], 32);
  oacc[0] += __shfl_xor(oacc[0], 16);
  oacc[1] += __shfl_xor(oacc[1], 32);
  oacc[1] += __shfl_xor(oacc[1], 16);
  if (lane < 16) {
    OB[wv][0][cl] = oacc[0];
    OB[wv][1][cl] = oacc[1];
  }
  __syncthreads();
  if (tid < 32) {
    const int grp = tid >> 4, b = tid & 15;
    float s = b_lin[0];
#pragma unroll
    for (int q = 0; q < 4; ++q) s += OB[q][grp][b];
    out[bbase + grp * 16 + b] = s;
  }
}

extern "C" void kernel_launch(void* const* d_in, const int* in_sizes, int n_in,
                              void* d_out, int out_size, void* d_ws, size_t ws_size,
                              hipStream_t stream) {
  const float* x     = (const float*)d_in[0];
  const float* w_ih  = (const float*)d_in[1];
  const float* w_hh  = (const float*)d_in[2];
  const float* b_ih  = (const float*)d_in[3];
  const float* b_hh  = (const float*)d_in[4];
  const float* w_lin = (const float*)d_in[5];
  const float* b_lin = (const float*)d_in[6];
  float* out = (float*)d_out;

  dim3 grid(16384 / 32);  // 512 blocks -> 2 per CU
  dim3 block(256);
  lstm_t13<<<grid, block, 0, stream>>>(x, w_ih, w_hh, b_ih, b_hh, w_lin,
                                       b_lin, out);
}